// Round 1
// baseline (82.576 us; speedup 1.0000x reference)
//
#include <hip/hip_runtime.h>

#define NPTS     4096
#define BQ       16
#define NTHREADS 256
#define CHUNK    2048   // inner points staged per LDS pass (32 KB as float4)

// One block = 256 outer points of one batch, one direction.
// dir 0: outer = preds, inner = gts  -> dl (min over gts per pred)
// dir 1: outer = gts,   inner = preds -> dr (min over preds per gt)
__global__ __launch_bounds__(NTHREADS, 2)
void chamfer_min_kernel(const float* __restrict__ preds,
                        const float* __restrict__ gts,
                        float* __restrict__ partial)
{
    __shared__ float4 s_pts[CHUNK];     // 32 KB
    __shared__ float  s_red[NTHREADS];  // 1 KB

    const int tile = blockIdx.x;   // 0..15
    const int b    = blockIdx.y;   // 0..15
    const int dir  = blockIdx.z;   // 0..1

    const float* outer = (dir == 0) ? preds : gts;
    const float* inner = (dir == 0) ? gts   : preds;
    const float* ob = outer + (size_t)b * NPTS * 3;
    const float* ib = inner + (size_t)b * NPTS * 3;

    // this thread's outer point
    const int   j  = tile * NTHREADS + (int)threadIdx.x;
    const float y0 = ob[j * 3 + 0];
    const float y1 = ob[j * 3 + 1];
    const float y2 = ob[j * 3 + 2];
    const float yy = y0 * y0 + y1 * y1 + y2 * y2;
    const float c0 = -2.0f * y0, c1 = -2.0f * y1, c2 = -2.0f * y2;

    // 8 independent min accumulators to break the dependence chain
    float m[8];
#pragma unroll
    for (int u = 0; u < 8; ++u) m[u] = 3.0e38f;

    for (int base = 0; base < NPTS; base += CHUNK) {
        // stage CHUNK inner points (+ squared norm) into LDS
        for (int idx = (int)threadIdx.x; idx < CHUNK; idx += NTHREADS) {
            const float* p = ib + (size_t)(base + idx) * 3;
            const float x0 = p[0], x1 = p[1], x2 = p[2];
            s_pts[idx] = make_float4(x0, x1, x2, x0 * x0 + x1 * x1 + x2 * x2);
        }
        __syncthreads();

#pragma unroll 1
        for (int i = 0; i < CHUNK; i += 8) {
#pragma unroll
            for (int u = 0; u < 8; ++u) {
                const float4 p = s_pts[i + u];   // wave-uniform -> LDS broadcast
                // xx_i - 2*dot(x_i, y_j)   (yy folded in after the loop)
                const float t = fmaf(c0, p.x, fmaf(c1, p.y, fmaf(c2, p.z, p.w)));
                m[u] = fminf(m[u], t);
            }
        }
        __syncthreads();
    }

    const float mv = fminf(fminf(fminf(m[0], m[1]), fminf(m[2], m[3])),
                           fminf(fminf(m[4], m[5]), fminf(m[6], m[7])));
    const float val = mv + yy;   // min_i ||x_i - y_j||^2

    // deterministic block tree-reduction of the 256 mins
    s_red[threadIdx.x] = val;
    __syncthreads();
#pragma unroll
    for (int s = NTHREADS / 2; s > 0; s >>= 1) {
        if ((int)threadIdx.x < s) s_red[threadIdx.x] += s_red[threadIdx.x + s];
        __syncthreads();
    }
    if (threadIdx.x == 0) {
        partial[(blockIdx.z * BQ + blockIdx.y) * (NPTS / NTHREADS) + blockIdx.x] = s_red[0];
    }
}

// Sum 512 block partials (2 dirs x 16 batches x 16 tiles), divide by B*N.
__global__ void chamfer_final_kernel(const float* __restrict__ partial,
                                     float* __restrict__ out)
{
    __shared__ float s_red[256];
    float v = partial[threadIdx.x] + partial[threadIdx.x + 256];
    s_red[threadIdx.x] = v;
    __syncthreads();
    for (int s = 128; s > 0; s >>= 1) {
        if ((int)threadIdx.x < s) s_red[threadIdx.x] += s_red[threadIdx.x + s];
        __syncthreads();
    }
    if (threadIdx.x == 0) out[0] = s_red[0] * (1.0f / (float)(BQ * NPTS));
}

extern "C" void kernel_launch(void* const* d_in, const int* in_sizes, int n_in,
                              void* d_out, int out_size, void* d_ws, size_t ws_size,
                              hipStream_t stream)
{
    const float* preds = (const float*)d_in[0];
    const float* gts   = (const float*)d_in[1];
    float* out     = (float*)d_out;
    float* partial = (float*)d_ws;   // 512 floats

    dim3 grid(NPTS / NTHREADS, BQ, 2);   // (16, 16, 2)
    chamfer_min_kernel<<<grid, NTHREADS, 0, stream>>>(preds, gts, partial);
    chamfer_final_kernel<<<1, 256, 0, stream>>>(partial, out);
}

// Round 2
// 69.039 us; speedup vs baseline: 1.1961x; 1.1961x over previous
//
#include <hip/hip_runtime.h>

#define NPTS  4096
#define BQ    16
#define NT    256
#define OPT   4                 // outer points per thread (register-blocked)
#define SEG   4                 // inner-dimension segments (for grid size)
#define SEGN  (NPTS / SEG)      // 1024 inner points per segment
#define OTILE (NT * OPT)        // 1024 outer points per block

// Pass 1: grid (NPTS/OTILE=4, SEG=4, 32=dir*16+b) = 512 blocks, 2/CU.
// Each block: 1024 outer points vs one 1024-point inner segment.
// Writes per-(outer,seg) partial min (yy folded in) to ws.
__global__ __launch_bounds__(NT, 2)
void chamfer_part_kernel(const float* __restrict__ preds,
                         const float* __restrict__ gts,
                         float* __restrict__ partial)
{
    __shared__ float4 s_pts[SEGN];   // 16 KB

    const int tile = blockIdx.x;          // 0..3
    const int seg  = blockIdx.y;          // 0..3
    const int bd   = blockIdx.z;          // 0..31
    const int dir  = bd >> 4;
    const int b    = bd & 15;

    const float* outer = (dir == 0) ? preds : gts;
    const float* inner = (dir == 0) ? gts   : preds;
    const float* ob = outer + (size_t)b * NPTS * 3;
    const float* ib = inner + (size_t)b * NPTS * 3 + (size_t)seg * SEGN * 3;

    // stage this inner segment into LDS as (x,y,z,||x||^2)
    for (int idx = (int)threadIdx.x; idx < SEGN; idx += NT) {
        const float x0 = ib[idx * 3 + 0];
        const float x1 = ib[idx * 3 + 1];
        const float x2 = ib[idx * 3 + 2];
        s_pts[idx] = make_float4(x0, x1, x2, x0 * x0 + x1 * x1 + x2 * x2);
    }

    // this thread's 4 outer points (coalesced per-u)
    float c0[OPT], c1[OPT], c2[OPT], yy[OPT];
#pragma unroll
    for (int u = 0; u < OPT; ++u) {
        const int o = tile * OTILE + u * NT + (int)threadIdx.x;
        const float y0 = ob[o * 3 + 0];
        const float y1 = ob[o * 3 + 1];
        const float y2 = ob[o * 3 + 2];
        yy[u] = y0 * y0 + y1 * y1 + y2 * y2;
        c0[u] = -2.0f * y0; c1[u] = -2.0f * y1; c2[u] = -2.0f * y2;
    }
    __syncthreads();

    float ma[OPT], mb[OPT];
#pragma unroll
    for (int u = 0; u < OPT; ++u) { ma[u] = 3.0e38f; mb[u] = 3.0e38f; }

#pragma unroll 1
    for (int i = 0; i < SEGN; i += 2) {
        const float4 pa = s_pts[i];       // wave-uniform -> broadcast
        const float4 pb = s_pts[i + 1];
#pragma unroll
        for (int u = 0; u < OPT; ++u) {
            const float ta = fmaf(c0[u], pa.x, fmaf(c1[u], pa.y, fmaf(c2[u], pa.z, pa.w)));
            ma[u] = fminf(ma[u], ta);
            const float tb = fmaf(c0[u], pb.x, fmaf(c1[u], pb.y, fmaf(c2[u], pb.z, pb.w)));
            mb[u] = fminf(mb[u], tb);
        }
    }

#pragma unroll
    for (int u = 0; u < OPT; ++u) {
        const int o = tile * OTILE + u * NT + (int)threadIdx.x;
        const float mv = fminf(ma[u], mb[u]) + yy[u];  // min ||x_i - y_j||^2 over this segment
        partial[((size_t)bd * NPTS + o) * SEG + seg] = mv;
    }
}

// Pass 2: 131072 slots; min over SEG=4 partials per slot, local sum, block reduce.
// grid 128 x 256, 4 slots/thread.
__global__ void chamfer_comb_kernel(const float* __restrict__ partial,
                                    float* __restrict__ blockpart)
{
    __shared__ float s_red[NT];
    float sum = 0.0f;
#pragma unroll
    for (int i = 0; i < 4; ++i) {
        const int slot = (int)blockIdx.x * 1024 + i * NT + (int)threadIdx.x;
        const float4 p = ((const float4*)partial)[slot];
        sum += fminf(fminf(p.x, p.y), fminf(p.z, p.w));
    }
    s_red[threadIdx.x] = sum;
    __syncthreads();
#pragma unroll
    for (int s = NT / 2; s > 0; s >>= 1) {
        if ((int)threadIdx.x < s) s_red[threadIdx.x] += s_red[threadIdx.x + s];
        __syncthreads();
    }
    if (threadIdx.x == 0) blockpart[blockIdx.x] = s_red[0];
}

// Pass 3: sum 128 block partials, scale by 1/(B*N).
__global__ void chamfer_final_kernel(const float* __restrict__ blockpart,
                                     float* __restrict__ out)
{
    __shared__ float s_red[128];
    s_red[threadIdx.x] = blockpart[threadIdx.x];
    __syncthreads();
#pragma unroll
    for (int s = 64; s > 0; s >>= 1) {
        if ((int)threadIdx.x < s) s_red[threadIdx.x] += s_red[threadIdx.x + s];
        __syncthreads();
    }
    if (threadIdx.x == 0) out[0] = s_red[0] * (1.0f / (float)(BQ * NPTS));
}

extern "C" void kernel_launch(void* const* d_in, const int* in_sizes, int n_in,
                              void* d_out, int out_size, void* d_ws, size_t ws_size,
                              hipStream_t stream)
{
    const float* preds = (const float*)d_in[0];
    const float* gts   = (const float*)d_in[1];
    float* out       = (float*)d_out;
    float* partial   = (float*)d_ws;                       // 2*16*4096*4 floats = 2 MB
    float* blockpart = partial + (size_t)2 * BQ * NPTS * SEG; // +128 floats

    dim3 grid1(NPTS / OTILE, SEG, 2 * BQ);   // (4, 4, 32) = 512 blocks
    chamfer_part_kernel<<<grid1, NT, 0, stream>>>(preds, gts, partial);
    chamfer_comb_kernel<<<128, NT, 0, stream>>>(partial, blockpart);
    chamfer_final_kernel<<<1, 128, 0, stream>>>(blockpart, out);
}